// Round 11
// baseline (153.574 us; speedup 1.0000x reference)
//
#include <hip/hip_runtime.h>
#include <math.h>

constexpr int CB   = 8;
constexpr int CN   = 2048;
constexpr int CD   = 8;
constexpr int CDEC = 128;
constexpr int CBN  = CB * CN;
constexpr int NWRD = CN / 64;   // 32 mask words per row
constexpr int JSP  = 32;        // j-split: part stays L2-resident
constexpr int JLEN = CN / JSP;  // 64

// lane-select: bit[lane] of wave-held mask selects p or 0
__device__ __forceinline__ float msel(unsigned long long m, int lane, float p) {
  return ((m >> lane) & 1ull) ? p : 0.f;
}

// ---------------- prep: h = xW, f1/f2, exps (round-5 verbatim) ----------------
__global__ void prep_k(const float* __restrict__ x,
                       const float* __restrict__ W, const float* __restrict__ a,
                       float4* __restrict__ pk, float4* __restrict__ qk) {
  int t = blockIdx.x * blockDim.x + threadIdx.x;
  if (t >= CBN) return;
  const float* xr = x + (size_t)t * CD;
  float h[CD];
#pragma unroll
  for (int d = 0; d < CD; ++d) {
    float s = 0.f;
#pragma unroll
    for (int k = 0; k < CD; ++k) s = fmaf(xr[k], W[k * CD + d], s);
    h[d] = s;
  }
  float s1 = 0.f, s2 = 0.f;
#pragma unroll
  for (int d = 0; d < CD; ++d) { s1 = fmaf(h[d], a[d], s1); s2 = fmaf(h[d], a[CD + d], s2); }
  pk[t] = make_float4(s1, expf(s1), expf(0.2f * s1), 0.f);
  qk[t] = make_float4(s2, expf(s2), expf(0.2f * s2), 0.f);
}

// -- mask build (transposed) + softmax row sums + inv_deg popcount (round-5) --
__global__ void mask_k(const int* __restrict__ adj, float4* __restrict__ pk,
                       const float4* __restrict__ qk, unsigned long long* __restrict__ maskT) {
  int gw   = (blockIdx.x * blockDim.x + threadIdx.x) >> 6;  // row index (b*CN+j)
  int lane = threadIdx.x & 63;
  if (gw >= CBN) return;
  int b = gw / CN, j = gw - b * CN;
  const int* arow = adj + (size_t)gw * CN;
  float4 pj = pk[gw];
  float f1j = pj.x;
  const float4* qb = qk + (size_t)b * CN;
  float A = 0.f, C = 0.f;
  int deg = 0;
  for (int k = 0; k < NWRD; ++k) {
    int i = k * 64 + lane;
    bool bit = arow[i] > 0;
    unsigned long long m = __ballot(bit);
    if (lane == 0) {
      maskT[((size_t)(b * NWRD + k)) * CN + j] = m;  // [b][word][j]
      deg += __popcll(m);
    }
    float4 q = qb[i];
    bool cond = (f1j + q.x) >= 0.f;
    A += (bit && cond) ? q.y : 0.f;
    C += (bit && !cond) ? q.z : 0.f;
  }
#pragma unroll
  for (int off = 32; off; off >>= 1) { A += __shfl_down(A, off); C += __shfl_down(C, off); }
  if (lane == 0) {
    float s = pj.y * A + pj.z * C;  // E1*sum_pos(E2) + F1*sum_neg(F2)
    float ga = (s > 0.f) ? pj.y / s : 0.f;
    float gb = (s > 0.f) ? pj.z / s : 0.f;
    float dv = 1.f / (float)(deg + 1);   // diag(inv_deg) for node j
    pk[gw] = make_float4(f1j, ga, gb, dv);
  }
}

// --- layer-1 aggregation (round-5 agg_k<8> verbatim): part1 = (agg x)@w1 ---
__global__ __launch_bounds__(256) void agg8_k(const float* __restrict__ feat,
                      const unsigned long long* __restrict__ maskT,
                      const float4* __restrict__ pk, const float4* __restrict__ qk,
                      const float* __restrict__ wmat, float* __restrict__ part) {
  const int js = blockIdx.x, ic = blockIdx.y, b = blockIdx.z;
  const int t = threadIdx.x;
  const int w = __builtin_amdgcn_readfirstlane(t >> 6);
  const int lane = t & 63;
  const int i1 = ic * 512 + t;   // slot 0
  const int i2 = i1 + 256;       // slot 1
  const int gi1 = b * CN + i1, gi2 = b * CN + i2;
  float4 q1 = qk[gi1], q2 = qk[gi2];
  const unsigned long long* mc1 = maskT + ((size_t)(b * NWRD + ic * 8 + w)) * CN + js * JLEN;
  const unsigned long long* mc2 = maskT + ((size_t)(b * NWRD + ic * 8 + 4 + w)) * CN + js * JLEN;
  const float4* pb = pk + (size_t)b * CN + js * JLEN;
  const float* fb  = feat + ((size_t)b * CN + js * JLEN) * 8;
  float acc1[8], acc2[8];
#pragma unroll
  for (int d = 0; d < 8; ++d) { acc1[d] = 0.f; acc2[d] = 0.f; }
#pragma unroll 4
  for (int jj = 0; jj < JLEN; ++jj) {
    unsigned long long m1 = mc1[jj];            // wave-uniform, contiguous stream
    unsigned long long m2 = mc2[jj];
    float4 pj = pb[jj];                         // {f1j, g1j, g2j, dv} uniform
    const float* fr = fb + jj * 8;              // uniform
    float wA = msel(m1, lane, fmaxf(pj.y * q1.y, pj.z * q1.z));
    float wB = msel(m2, lane, fmaxf(pj.y * q2.y, pj.z * q2.z));
#pragma unroll
    for (int d = 0; d < 8; ++d) {
      acc1[d] = fmaf(wA, fr[d], acc1[d]);
      acc2[d] = fmaf(wB, fr[d], acc2[d]);
    }
  }
  float o1[8], o2[8];
#pragma unroll
  for (int o = 0; o < 8; ++o) {
    float s1 = 0.f, s2 = 0.f;
#pragma unroll
    for (int d = 0; d < 8; ++d) {
      s1 = fmaf(acc1[d], wmat[d * 8 + o], s1);
      s2 = fmaf(acc2[d], wmat[d * 8 + o], s2);
    }
    o1[o] = s1;
    o2[o] = s2;
  }
  float4* p1 = (float4*)(part + ((size_t)js * CBN + gi1) * 8);
  float4* p2 = (float4*)(part + ((size_t)js * CBN + gi2) * 8);
  p1[0] = make_float4(o1[0], o1[1], o1[2], o1[3]);
  p1[1] = make_float4(o1[4], o1[5], o1[6], o1[7]);
  p2[0] = make_float4(o2[0], o2[1], o2[2], o2[3]);
  p2[1] = make_float4(o2[4], o2[5], o2[6], o2[7]);
}

// --- fused epi8 + layer-2 aggregation: compute out1 rows of this j-chunk in
// LDS (from part1), then aggregate them; part2 = (agg out1)@w2 ---
__global__ __launch_bounds__(256) void agg16e_k(
    const float* __restrict__ x, const float* __restrict__ part1,
    const unsigned long long* __restrict__ maskT,
    const float4* __restrict__ pk, const float4* __restrict__ qk,
    const float* __restrict__ b1, const float* __restrict__ w2,
    float* __restrict__ out1, float* __restrict__ part2) {
  __shared__ float flds[JLEN * 16];
  __shared__ float piece[4][JLEN][8];
  const int js = blockIdx.x, ic = blockIdx.y, b = blockIdx.z;
  const int t = threadIdx.x;
  const int w = __builtin_amdgcn_readfirstlane(t >> 6);
  const int lane = t & 63;
  // ---- epi8 for the 64 rows of this chunk: 4 pieces of 8 partials each ----
  {
    int r = t & 63, p4 = t >> 6;
    float s0=0.f,s1=0.f,s2=0.f,s3=0.f,s4=0.f,s5=0.f,s6=0.f,s7=0.f;
    for (int p = p4 * 8; p < p4 * 8 + 8; ++p) {
      const float4* pr = (const float4*)(part1 + ((size_t)p * CBN + b * CN + js * JLEN + r) * 8);
      float4 r0 = pr[0], r1 = pr[1];
      s0 += r0.x; s1 += r0.y; s2 += r0.z; s3 += r0.w;
      s4 += r1.x; s5 += r1.y; s6 += r1.z; s7 += r1.w;
    }
    piece[p4][r][0]=s0; piece[p4][r][1]=s1; piece[p4][r][2]=s2; piece[p4][r][3]=s3;
    piece[p4][r][4]=s4; piece[p4][r][5]=s5; piece[p4][r][6]=s6; piece[p4][r][7]=s7;
  }
  __syncthreads();
  if (t < JLEN) {
    int gr = b * CN + js * JLEN + t;
    float ag[8];
#pragma unroll
    for (int o = 0; o < 8; ++o)
      ag[o] = piece[0][t][o] + piece[1][t][o] + piece[2][t][o] + piece[3][t][o];
    float dv = pk[gr].w;
    const float* xr = x + (size_t)gr * CD;
    float c[16];
#pragma unroll
    for (int o = 0; o < 8; ++o) {
      float s2 = 0.f;
#pragma unroll
      for (int d = 0; d < 8; ++d) s2 = fmaf(xr[d], b1[d * 8 + o], s2);
      c[o] = ag[o] * dv;
      c[8 + o] = s2;
    }
    float nn = 0.f;
#pragma unroll
    for (int k = 0; k < 16; ++k) nn += c[k] * c[k];
    float inv = 1.f / fmaxf(sqrtf(nn), 1e-12f);
#pragma unroll
    for (int k = 0; k < 16; ++k) {
      float v = c[k] * inv;
      flds[t * 16 + k] = (v >= 0.f) ? v : 0.1f * v;   // leaky 0.1
    }
    if (ic == 0) {   // materialize out1 once (needed by fused3e's self terms)
      float4* orow = (float4*)(out1 + (size_t)gr * 16);
#pragma unroll
      for (int q = 0; q < 4; ++q)
        orow[q] = make_float4(flds[t*16+q*4], flds[t*16+q*4+1],
                              flds[t*16+q*4+2], flds[t*16+q*4+3]);
    }
  }
  __syncthreads();
  // ---- layer-2 aggregation over the chunk (feat rows from LDS) ----
  const int i1 = ic * 512 + t, i2 = i1 + 256;
  const int gi1 = b * CN + i1, gi2 = b * CN + i2;
  const float4 q1 = qk[gi1], q2 = qk[gi2];
  const unsigned long long* mc1 = maskT + ((size_t)(b * NWRD + ic * 8 + w)) * CN + js * JLEN;
  const unsigned long long* mc2 = maskT + ((size_t)(b * NWRD + ic * 8 + 4 + w)) * CN + js * JLEN;
  const float4* pb = pk + (size_t)b * CN + js * JLEN;
  float acc1[16], acc2[16];
#pragma unroll
  for (int d = 0; d < 16; ++d) { acc1[d] = 0.f; acc2[d] = 0.f; }
#pragma unroll 4
  for (int jj = 0; jj < JLEN; ++jj) {
    unsigned long long m1 = mc1[jj];
    unsigned long long m2 = mc2[jj];
    float4 pj = pb[jj];
    const float* fr = flds + jj * 16;
    float wA = msel(m1, lane, fmaxf(pj.y * q1.y, pj.z * q1.z));
    float wB = msel(m2, lane, fmaxf(pj.y * q2.y, pj.z * q2.z));
#pragma unroll
    for (int d = 0; d < 16; ++d) {
      acc1[d] = fmaf(wA, fr[d], acc1[d]);
      acc2[d] = fmaf(wB, fr[d], acc2[d]);
    }
  }
  float o1[8], o2[8];
#pragma unroll
  for (int o = 0; o < 8; ++o) {
    float s1 = 0.f, s2 = 0.f;
#pragma unroll
    for (int d = 0; d < 16; ++d) {
      s1 = fmaf(acc1[d], w2[d * 8 + o], s1);
      s2 = fmaf(acc2[d], w2[d * 8 + o], s2);
    }
    o1[o] = s1;
    o2[o] = s2;
  }
  float4* p1 = (float4*)(part2 + ((size_t)js * CBN + gi1) * 8);
  float4* p2 = (float4*)(part2 + ((size_t)js * CBN + gi2) * 8);
  p1[0] = make_float4(o1[0], o1[1], o1[2], o1[3]);
  p1[1] = make_float4(o1[4], o1[5], o1[6], o1[7]);
  p2[0] = make_float4(o2[0], o2[1], o2[2], o2[3]);
  p2[1] = make_float4(o2[4], o2[5], o2[6], o2[7]);
}

// ---- fused epi16 + layer 3 + decoder: out2 rows computed inline ----
__global__ __launch_bounds__(512) void fused3e_k(
    const float* __restrict__ out1, const float* __restrict__ part2,
    const unsigned long long* __restrict__ maskT,
    const float4* __restrict__ pk, const float4* __restrict__ qk,
    const float* __restrict__ b2, const float* __restrict__ w3,
    const float* __restrict__ b3, const float* __restrict__ P1,
    const float* __restrict__ P2, float* __restrict__ y) {
  constexpr int NT = 512;
  __shared__ float redA[NT / 64][16], redB[NT / 64][16];
  __shared__ float agA[16], agB[16], cA[16], cB[16], daF[16], dbF[16];
  __shared__ float selfA[16], selfB[16];
  __shared__ float vsh[CDEC], red[CDEC];
  const int b = blockIdx.x;
  const int t = threadIdx.x;
  const int lane = t & 63, wv = t >> 6;  // 8 waves
  const int ia = CN - 2, ib = CN - 1;
  float4 qa = qk[b * CN + ia], qb = qk[b * CN + ib];
  float dva = pk[b * CN + ia].w, dvb = pk[b * CN + ib].w;
  float accA[16], accB[16];
#pragma unroll
  for (int d = 0; d < 16; ++d) { accA[d] = 0.f; accB[d] = 0.f; }
  const unsigned long long* mrow = maskT + ((size_t)(b * NWRD + (NWRD - 1))) * CN;
  for (int j = t; j < CN; j += NT) {
    // --- inline epi16: out2 row j ---
    float ag[8] = {0.f,0.f,0.f,0.f,0.f,0.f,0.f,0.f};
    for (int p = 0; p < JSP; ++p) {
      const float4* pr = (const float4*)(part2 + ((size_t)p * CBN + b * CN + j) * 8);
      float4 r0 = pr[0], r1 = pr[1];
      ag[0] += r0.x; ag[1] += r0.y; ag[2] += r0.z; ag[3] += r0.w;
      ag[4] += r1.x; ag[5] += r1.y; ag[6] += r1.z; ag[7] += r1.w;
    }
    float dv = pk[b * CN + j].w;
    const float4* o1p = (const float4*)(out1 + (size_t)(b * CN + j) * 16);
    float4 g0 = o1p[0], g1 = o1p[1], g2 = o1p[2], g3 = o1p[3];
    float of[16] = {g0.x,g0.y,g0.z,g0.w, g1.x,g1.y,g1.z,g1.w,
                    g2.x,g2.y,g2.z,g2.w, g3.x,g3.y,g3.z,g3.w};
    float c[16];
#pragma unroll
    for (int o = 0; o < 8; ++o) {
      float s2 = 0.f;
#pragma unroll
      for (int d = 0; d < 16; ++d) s2 = fmaf(of[d], b2[d * 8 + o], s2);
      c[o] = ag[o] * dv;
      c[8 + o] = s2;
    }
    float nn = 0.f;
#pragma unroll
    for (int k = 0; k < 16; ++k) nn += c[k] * c[k];
    float inv = 1.f / fmaxf(sqrtf(nn), 1e-12f);
    float ff[16];
#pragma unroll
    for (int k = 0; k < 16; ++k) {
      float v = c[k] * inv;
      ff[k] = (v >= 0.f) ? v : 0.1f * v;
    }
    if (j == ia) {
#pragma unroll
      for (int d = 0; d < 16; ++d) selfA[d] = ff[d];
    }
    if (j == ib) {
#pragma unroll
      for (int d = 0; d < 16; ++d) selfB[d] = ff[d];
    }
    // --- layer-3 accumulation for target rows ia, ib ---
    unsigned long long m = mrow[j];
    float4 pj = pk[b * CN + j];
    float wA = fmaxf(pj.y * qa.y, pj.z * qa.z);
    wA = ((m >> 62) & 1ull) ? wA : 0.f;     // bit for i = N-2
    float wB = fmaxf(pj.y * qb.y, pj.z * qb.z);
    wB = (m >> 63) ? wB : 0.f;              // bit for i = N-1
#pragma unroll
    for (int d = 0; d < 16; ++d) {
      accA[d] = fmaf(wA, ff[d], accA[d]);
      accB[d] = fmaf(wB, ff[d], accB[d]);
    }
  }
#pragma unroll
  for (int d = 0; d < 16; ++d) {
#pragma unroll
    for (int off = 32; off; off >>= 1) {
      accA[d] += __shfl_down(accA[d], off);
      accB[d] += __shfl_down(accB[d], off);
    }
  }
  if (lane == 0) {
#pragma unroll
    for (int d = 0; d < 16; ++d) { redA[wv][d] = accA[d]; redB[wv][d] = accB[d]; }
  }
  __syncthreads();
  if (t < 16) {
    float sA = 0.f, sB = 0.f;
#pragma unroll
    for (int w_ = 0; w_ < NT / 64; ++w_) { sA += redA[w_][t]; sB += redB[w_][t]; }
    agA[t] = sA * dva;   // inv_deg scale
    agB[t] = sB * dvb;
  }
  __syncthreads();
  if (t < 32) {
    int row = t >> 4, k = t & 15;
    const float* ag = row ? agB : agA;
    const float* self = row ? selfB : selfA;
    float s = 0.f;
    if (k < 8) {
#pragma unroll
      for (int d = 0; d < 16; ++d) s = fmaf(ag[d], w3[d * 8 + k], s);
    } else {
#pragma unroll
      for (int d = 0; d < 16; ++d) s = fmaf(self[d], b3[d * 8 + (k - 8)], s);
    }
    (row ? cB : cA)[k] = s;
  }
  __syncthreads();
  if (t < 32) {
    int row = t >> 4, k = t & 15;
    const float* c = row ? cB : cA;
    float nn = 0.f;
#pragma unroll
    for (int q = 0; q < 16; ++q) nn += c[q] * c[q];
    float inv = 1.f / fmaxf(sqrtf(nn), 1e-12f);
    float v = c[k] * inv;
    (row ? dbF : daF)[k] = (v >= 0.f) ? v : 0.1f * v;
  }
  __syncthreads();
  float ue = 0.f, ve = 0.f;
  if (t < CDEC) {
#pragma unroll
    for (int i = 0; i < 16; ++i) {
      ue = fmaf(daF[i], P1[i * CDEC + t], ue);
      ve = fmaf(dbF[i], P1[i * CDEC + t], ve);
    }
    vsh[t] = ve;
  }
  __syncthreads();
  if (t < CDEC) {
    float s = 0.f;
    for (int e2 = 0; e2 < CDEC; ++e2) s = fmaf(P2[t * CDEC + e2], vsh[e2], s);
    red[t] = s * ue;
  }
  __syncthreads();
  for (int off = 64; off; off >>= 1) {
    if (t < off) red[t] += red[t + off];
    __syncthreads();
  }
  if (t == 0) y[b] = red[0];
}

extern "C" void kernel_launch(void* const* d_in, const int* in_sizes, int n_in,
                              void* d_out, int out_size, void* d_ws, size_t ws_size,
                              hipStream_t stream) {
  const float* x  = (const float*)d_in[0];
  const int*   adj = (const int*)d_in[1];
  const float* W  = (const float*)d_in[3];
  const float* a  = (const float*)d_in[4];
  const float* w1 = (const float*)d_in[5];
  const float* b1 = (const float*)d_in[6];
  const float* w2 = (const float*)d_in[7];
  const float* b2 = (const float*)d_in[8];
  const float* w3 = (const float*)d_in[9];
  const float* b3 = (const float*)d_in[10];
  const float* P1 = (const float*)d_in[11];
  const float* P2 = (const float*)d_in[12];
  float* y = (float*)d_out;

  char* base = (char*)d_ws;
  size_t off = 0;
  auto alloc = [&](size_t bytes) -> void* {
    void* r = base + off;
    off += (bytes + 255) & ~(size_t)255;
    return r;
  };
  float4* pk = (float4*)alloc(sizeof(float4) * CBN);
  float4* qk = (float4*)alloc(sizeof(float4) * CBN);
  unsigned long long* maskT =
      (unsigned long long*)alloc(sizeof(unsigned long long) * (size_t)CBN * NWRD);
  float* out1  = (float*)alloc(sizeof(float) * (size_t)CBN * 16);
  float* part1 = (float*)alloc(sizeof(float) * (size_t)JSP * CBN * 8);
  float* part2 = (float*)alloc(sizeof(float) * (size_t)JSP * CBN * 8);

  hipLaunchKernelGGL(prep_k, dim3(CBN / 256), dim3(256), 0, stream, x, W, a, pk, qk);
  hipLaunchKernelGGL(mask_k, dim3(CBN / 4), dim3(256), 0, stream, adj, pk, qk, maskT);
  hipLaunchKernelGGL(agg8_k, dim3(JSP, 4, CB), dim3(256), 0, stream, x, maskT, pk, qk, w1, part1);
  hipLaunchKernelGGL(agg16e_k, dim3(JSP, 4, CB), dim3(256), 0, stream,
                     x, part1, maskT, pk, qk, b1, w2, out1, part2);
  hipLaunchKernelGGL(fused3e_k, dim3(CB), dim3(512), 0, stream,
                     out1, part2, maskT, pk, qk, b2, w3, b3, P1, P2, y);
}

// Round 12
// 135.584 us; speedup vs baseline: 1.1327x; 1.1327x over previous
//
#include <hip/hip_runtime.h>
#include <math.h>

constexpr int CB   = 8;
constexpr int CN   = 2048;
constexpr int CD   = 8;
constexpr int CDEC = 128;
constexpr int CBN  = CB * CN;
constexpr int NWRD = CN / 64;   // 32 mask words per row
constexpr int JSP  = 32;        // j-split: part stays L2-resident
constexpr int JLEN = CN / JSP;  // 64

__device__ __forceinline__ float msel(unsigned long long m, int lane, float p) {
  return ((m >> lane) & 1ull) ? p : 0.f;
}

// ---------------- prep: h = xW, f1/f2, exps ----------------
__global__ void prep_k(const float* __restrict__ x,
                       const float* __restrict__ W, const float* __restrict__ a,
                       float4* __restrict__ pk, float4* __restrict__ qk) {
  int t = blockIdx.x * blockDim.x + threadIdx.x;
  if (t >= CBN) return;
  const float* xr = x + (size_t)t * CD;
  float h[CD];
#pragma unroll
  for (int d = 0; d < CD; ++d) {
    float s = 0.f;
#pragma unroll
    for (int k = 0; k < CD; ++k) s = fmaf(xr[k], W[k * CD + d], s);
    h[d] = s;
  }
  float s1 = 0.f, s2 = 0.f;
#pragma unroll
  for (int d = 0; d < CD; ++d) { s1 = fmaf(h[d], a[d], s1); s2 = fmaf(h[d], a[CD + d], s2); }
  pk[t] = make_float4(s1, expf(s1), expf(0.2f * s1), 0.f);
  qk[t] = make_float4(s2, expf(s2), expf(0.2f * s2), 0.f);
}

// ---- maskb: pure adj -> transposed bitmask (HBM-bound, nothing else) ----
__global__ void maskb_k(const int* __restrict__ adj, unsigned long long* __restrict__ maskT) {
  int gw   = (blockIdx.x * blockDim.x + threadIdx.x) >> 6;  // row (b*CN+j)
  int lane = threadIdx.x & 63;
  if (gw >= CBN) return;
  int b = gw / CN, j = gw - b * CN;
  const int* arow = adj + (size_t)gw * CN;
  for (int k = 0; k < NWRD; ++k) {
    bool bit = arow[k * 64 + lane] > 0;
    unsigned long long m = __ballot(bit);
    if (lane == 0) maskT[((size_t)(b * NWRD + k)) * CN + j] = m;  // [b][word][j]
  }
}

// ---- rowsum: transposed softmax row-sums + deg from popcount; finalize pk ----
// block: 256 thr = 4 waves; each block owns 64 j's; waves split the 32 words.
__global__ __launch_bounds__(256) void rowsum_k(
    const unsigned long long* __restrict__ maskT,
    float4* __restrict__ pk, const float4* __restrict__ qk) {
  __shared__ float As[4][64], Cs[4][64];
  __shared__ int   Ds[4][64];
  const int b = blockIdx.x >> 5;                // 32 blocks per batch
  const int jbase = (blockIdx.x & 31) << 6;
  const int t = threadIdx.x;
  const int lane = t & 63, wv = t >> 6;
  const int j = jbase + lane;
  const float f1j = pk[b * CN + j].x;           // per-lane
  const float4* qb = qk + (size_t)b * CN;
  float A = 0.f, C = 0.f;
  int deg = 0;
  for (int k = wv * 8; k < wv * 8 + 8; ++k) {
    unsigned long long w = maskT[((size_t)(b * NWRD + k)) * CN + j];  // per-lane
    deg += __popcll(w);
#pragma unroll 8
    for (int ii = 0; ii < 64; ++ii) {
      float4 q = qb[k * 64 + ii];               // wave-uniform -> s_load
      bool cond = (f1j + q.x) >= 0.f;
      bool bit = (w >> ii) & 1ull;
      A += (bit && cond) ? q.y : 0.f;
      C += (bit && !cond) ? q.z : 0.f;
    }
  }
  As[wv][lane] = A; Cs[wv][lane] = C; Ds[wv][lane] = deg;
  __syncthreads();
  if (t < 64) {
    float sA = As[0][t] + As[1][t] + As[2][t] + As[3][t];
    float sC = Cs[0][t] + Cs[1][t] + Cs[2][t] + Cs[3][t];
    int   sd = Ds[0][t] + Ds[1][t] + Ds[2][t] + Ds[3][t];
    int gr = b * CN + jbase + t;
    float4 pj = pk[gr];
    float s = pj.y * sA + pj.z * sC;            // E1*sum_pos + F1*sum_neg
    float ga = (s > 0.f) ? pj.y / s : 0.f;
    float gb = (s > 0.f) ? pj.z / s : 0.f;
    float dv = 1.f / (float)(sd + 1);
    pk[gr] = make_float4(pj.x, ga, gb, dv);
  }
}

// --- layer-1 aggregation: part1 = (agg x)@w1 (round-5 verbatim) ---
__global__ __launch_bounds__(256) void agg8_k(const float* __restrict__ feat,
                      const unsigned long long* __restrict__ maskT,
                      const float4* __restrict__ pk, const float4* __restrict__ qk,
                      const float* __restrict__ wmat, float* __restrict__ part) {
  const int js = blockIdx.x, ic = blockIdx.y, b = blockIdx.z;
  const int t = threadIdx.x;
  const int w = __builtin_amdgcn_readfirstlane(t >> 6);
  const int lane = t & 63;
  const int i1 = ic * 512 + t, i2 = i1 + 256;
  const int gi1 = b * CN + i1, gi2 = b * CN + i2;
  float4 q1 = qk[gi1], q2 = qk[gi2];
  const unsigned long long* mc1 = maskT + ((size_t)(b * NWRD + ic * 8 + w)) * CN + js * JLEN;
  const unsigned long long* mc2 = maskT + ((size_t)(b * NWRD + ic * 8 + 4 + w)) * CN + js * JLEN;
  const float4* pb = pk + (size_t)b * CN + js * JLEN;
  const float* fb  = feat + ((size_t)b * CN + js * JLEN) * 8;
  float acc1[8], acc2[8];
#pragma unroll
  for (int d = 0; d < 8; ++d) { acc1[d] = 0.f; acc2[d] = 0.f; }
#pragma unroll 4
  for (int jj = 0; jj < JLEN; ++jj) {
    unsigned long long m1 = mc1[jj];
    unsigned long long m2 = mc2[jj];
    float4 pj = pb[jj];
    const float* fr = fb + jj * 8;
    float wA = msel(m1, lane, fmaxf(pj.y * q1.y, pj.z * q1.z));
    float wB = msel(m2, lane, fmaxf(pj.y * q2.y, pj.z * q2.z));
#pragma unroll
    for (int d = 0; d < 8; ++d) {
      acc1[d] = fmaf(wA, fr[d], acc1[d]);
      acc2[d] = fmaf(wB, fr[d], acc2[d]);
    }
  }
  float o1[8], o2[8];
#pragma unroll
  for (int o = 0; o < 8; ++o) {
    float s1 = 0.f, s2 = 0.f;
#pragma unroll
    for (int d = 0; d < 8; ++d) {
      s1 = fmaf(acc1[d], wmat[d * 8 + o], s1);
      s2 = fmaf(acc2[d], wmat[d * 8 + o], s2);
    }
    o1[o] = s1;
    o2[o] = s2;
  }
  float4* p1 = (float4*)(part + ((size_t)js * CBN + gi1) * 8);
  float4* p2 = (float4*)(part + ((size_t)js * CBN + gi2) * 8);
  p1[0] = make_float4(o1[0], o1[1], o1[2], o1[3]);
  p1[1] = make_float4(o1[4], o1[5], o1[6], o1[7]);
  p2[0] = make_float4(o2[0], o2[1], o2[2], o2[3]);
  p2[1] = make_float4(o2[4], o2[5], o2[6], o2[7]);
}

// --- fused epi8 + layer-2 aggregation (round-11 verbatim; it passed) ---
__global__ __launch_bounds__(256) void agg16e_k(
    const float* __restrict__ x, const float* __restrict__ part1,
    const unsigned long long* __restrict__ maskT,
    const float4* __restrict__ pk, const float4* __restrict__ qk,
    const float* __restrict__ b1, const float* __restrict__ w2,
    float* __restrict__ out1, float* __restrict__ part2) {
  __shared__ float flds[JLEN * 16];
  __shared__ float piece[4][JLEN][8];
  const int js = blockIdx.x, ic = blockIdx.y, b = blockIdx.z;
  const int t = threadIdx.x;
  const int w = __builtin_amdgcn_readfirstlane(t >> 6);
  const int lane = t & 63;
  {
    int r = t & 63, p4 = t >> 6;
    float s0=0.f,s1=0.f,s2=0.f,s3=0.f,s4=0.f,s5=0.f,s6=0.f,s7=0.f;
    for (int p = p4 * 8; p < p4 * 8 + 8; ++p) {
      const float4* pr = (const float4*)(part1 + ((size_t)p * CBN + b * CN + js * JLEN + r) * 8);
      float4 r0 = pr[0], r1 = pr[1];
      s0 += r0.x; s1 += r0.y; s2 += r0.z; s3 += r0.w;
      s4 += r1.x; s5 += r1.y; s6 += r1.z; s7 += r1.w;
    }
    piece[p4][r][0]=s0; piece[p4][r][1]=s1; piece[p4][r][2]=s2; piece[p4][r][3]=s3;
    piece[p4][r][4]=s4; piece[p4][r][5]=s5; piece[p4][r][6]=s6; piece[p4][r][7]=s7;
  }
  __syncthreads();
  if (t < JLEN) {
    int gr = b * CN + js * JLEN + t;
    float ag[8];
#pragma unroll
    for (int o = 0; o < 8; ++o)
      ag[o] = piece[0][t][o] + piece[1][t][o] + piece[2][t][o] + piece[3][t][o];
    float dv = pk[gr].w;
    const float* xr = x + (size_t)gr * CD;
    float c[16];
#pragma unroll
    for (int o = 0; o < 8; ++o) {
      float s2 = 0.f;
#pragma unroll
      for (int d = 0; d < 8; ++d) s2 = fmaf(xr[d], b1[d * 8 + o], s2);
      c[o] = ag[o] * dv;
      c[8 + o] = s2;
    }
    float nn = 0.f;
#pragma unroll
    for (int k = 0; k < 16; ++k) nn += c[k] * c[k];
    float inv = 1.f / fmaxf(sqrtf(nn), 1e-12f);
#pragma unroll
    for (int k = 0; k < 16; ++k) {
      float v = c[k] * inv;
      flds[t * 16 + k] = (v >= 0.f) ? v : 0.1f * v;
    }
    if (ic == 0) {
      float4* orow = (float4*)(out1 + (size_t)gr * 16);
#pragma unroll
      for (int q = 0; q < 4; ++q)
        orow[q] = make_float4(flds[t*16+q*4], flds[t*16+q*4+1],
                              flds[t*16+q*4+2], flds[t*16+q*4+3]);
    }
  }
  __syncthreads();
  const int i1 = ic * 512 + t, i2 = i1 + 256;
  const int gi1 = b * CN + i1, gi2 = b * CN + i2;
  const float4 q1 = qk[gi1], q2 = qk[gi2];
  const unsigned long long* mc1 = maskT + ((size_t)(b * NWRD + ic * 8 + w)) * CN + js * JLEN;
  const unsigned long long* mc2 = maskT + ((size_t)(b * NWRD + ic * 8 + 4 + w)) * CN + js * JLEN;
  const float4* pb = pk + (size_t)b * CN + js * JLEN;
  float acc1[16], acc2[16];
#pragma unroll
  for (int d = 0; d < 16; ++d) { acc1[d] = 0.f; acc2[d] = 0.f; }
#pragma unroll 4
  for (int jj = 0; jj < JLEN; ++jj) {
    unsigned long long m1 = mc1[jj];
    unsigned long long m2 = mc2[jj];
    float4 pj = pb[jj];
    const float* fr = flds + jj * 16;
    float wA = msel(m1, lane, fmaxf(pj.y * q1.y, pj.z * q1.z));
    float wB = msel(m2, lane, fmaxf(pj.y * q2.y, pj.z * q2.z));
#pragma unroll
    for (int d = 0; d < 16; ++d) {
      acc1[d] = fmaf(wA, fr[d], acc1[d]);
      acc2[d] = fmaf(wB, fr[d], acc2[d]);
    }
  }
  float o1[8], o2[8];
#pragma unroll
  for (int o = 0; o < 8; ++o) {
    float s1 = 0.f, s2 = 0.f;
#pragma unroll
    for (int d = 0; d < 16; ++d) {
      s1 = fmaf(acc1[d], w2[d * 8 + o], s1);
      s2 = fmaf(acc2[d], w2[d * 8 + o], s2);
    }
    o1[o] = s1;
    o2[o] = s2;
  }
  float4* p1 = (float4*)(part2 + ((size_t)js * CBN + gi1) * 8);
  float4* p2 = (float4*)(part2 + ((size_t)js * CBN + gi2) * 8);
  p1[0] = make_float4(o1[0], o1[1], o1[2], o1[3]);
  p1[1] = make_float4(o1[4], o1[5], o1[6], o1[7]);
  p2[0] = make_float4(o2[0], o2[1], o2[2], o2[3]);
  p2[1] = make_float4(o2[4], o2[5], o2[6], o2[7]);
}

// ---- epi16f: out2 row in registers + layer-3 partial fold (64 blocks) ----
// gpart[b][blk8][2][16]; self2[b][2][16]; out2 never materialized.
__global__ __launch_bounds__(256) void epi16f_k(
    const float* __restrict__ out1, const float* __restrict__ part2,
    const unsigned long long* __restrict__ maskT,
    const float4* __restrict__ pk, const float4* __restrict__ qk,
    const float* __restrict__ b2,
    float* __restrict__ gpart, float* __restrict__ self2) {
  __shared__ float redA[4][16], redB[4][16];
  const int t = threadIdx.x;
  const int lane = t & 63, wv = t >> 6;
  const int gr = blockIdx.x * 256 + t;
  const int b = blockIdx.x >> 3, blk8 = blockIdx.x & 7;
  const int j = gr - b * CN;
  const int ia = CN - 2, ib = CN - 1;
  // inline epi16: out2 row gr
  float ag[8] = {0.f,0.f,0.f,0.f,0.f,0.f,0.f,0.f};
  for (int p = 0; p < JSP; ++p) {
    const float4* pr = (const float4*)(part2 + ((size_t)p * CBN + gr) * 8);
    float4 r0 = pr[0], r1 = pr[1];
    ag[0] += r0.x; ag[1] += r0.y; ag[2] += r0.z; ag[3] += r0.w;
    ag[4] += r1.x; ag[5] += r1.y; ag[6] += r1.z; ag[7] += r1.w;
  }
  float4 pj = pk[gr];
  const float4* o1p = (const float4*)(out1 + (size_t)gr * 16);
  float4 g0 = o1p[0], g1 = o1p[1], g2 = o1p[2], g3 = o1p[3];
  float of[16] = {g0.x,g0.y,g0.z,g0.w, g1.x,g1.y,g1.z,g1.w,
                  g2.x,g2.y,g2.z,g2.w, g3.x,g3.y,g3.z,g3.w};
  float c[16];
#pragma unroll
  for (int o = 0; o < 8; ++o) {
    float s2 = 0.f;
#pragma unroll
    for (int d = 0; d < 16; ++d) s2 = fmaf(of[d], b2[d * 8 + o], s2);
    c[o] = ag[o] * pj.w;
    c[8 + o] = s2;
  }
  float nn = 0.f;
#pragma unroll
  for (int k = 0; k < 16; ++k) nn += c[k] * c[k];
  float inv = 1.f / fmaxf(sqrtf(nn), 1e-12f);
  float ff[16];
#pragma unroll
  for (int k = 0; k < 16; ++k) {
    float v = c[k] * inv;
    ff[k] = (v >= 0.f) ? v : 0.1f * v;
  }
  if (j == ia || j == ib) {
    float* s = self2 + ((size_t)b * 2 + (j == ib ? 1 : 0)) * 16;
#pragma unroll
    for (int d = 0; d < 16; ++d) s[d] = ff[d];
  }
  // layer-3 contribution of row j to targets ia, ib
  unsigned long long m = maskT[((size_t)(b * NWRD + (NWRD - 1))) * CN + j];
  float4 qa = qk[b * CN + ia], qb = qk[b * CN + ib];   // block-uniform
  float wA = ((m >> 62) & 1ull) ? fmaxf(pj.y * qa.y, pj.z * qa.z) : 0.f;
  float wB = (m >> 63) ? fmaxf(pj.y * qb.y, pj.z * qb.z) : 0.f;
  float accA[16], accB[16];
#pragma unroll
  for (int d = 0; d < 16; ++d) { accA[d] = wA * ff[d]; accB[d] = wB * ff[d]; }
#pragma unroll
  for (int d = 0; d < 16; ++d) {
#pragma unroll
    for (int off = 32; off; off >>= 1) {
      accA[d] += __shfl_down(accA[d], off);
      accB[d] += __shfl_down(accB[d], off);
    }
  }
  if (lane == 0) {
#pragma unroll
    for (int d = 0; d < 16; ++d) { redA[wv][d] = accA[d]; redB[wv][d] = accB[d]; }
  }
  __syncthreads();
  if (t < 32) {
    int row = t >> 4, k = t & 15;
    float s = row ? (redB[0][k] + redB[1][k] + redB[2][k] + redB[3][k])
                  : (redA[0][k] + redA[1][k] + redA[2][k] + redA[3][k]);
    gpart[(((size_t)b * 8 + blk8) * 2 + row) * 16 + k] = s;
  }
}

// ---- dec: reduce gpart, w3/b3, norm, leaky, bilinear decoder (8 blocks) ----
__global__ __launch_bounds__(CDEC) void dec_k(
    const float* __restrict__ gpart, const float* __restrict__ self2,
    const float4* __restrict__ pk,
    const float* __restrict__ w3, const float* __restrict__ b3,
    const float* __restrict__ P1, const float* __restrict__ P2,
    float* __restrict__ y) {
  __shared__ float agA[16], agB[16], cA[16], cB[16], daF[16], dbF[16];
  __shared__ float vsh[CDEC], red[CDEC];
  const int b = blockIdx.x;
  const int t = threadIdx.x;
  const int ia = CN - 2, ib = CN - 1;
  if (t < 32) {
    int row = t >> 4, k = t & 15;
    float s = 0.f;
#pragma unroll
    for (int blk = 0; blk < 8; ++blk)
      s += gpart[(((size_t)b * 8 + blk) * 2 + row) * 16 + k];
    float dv = pk[b * CN + (row ? ib : ia)].w;
    (row ? agB : agA)[k] = s * dv;
  }
  __syncthreads();
  if (t < 32) {
    int row = t >> 4, k = t & 15;
    const float* ag = row ? agB : agA;
    const float* self = self2 + ((size_t)b * 2 + row) * 16;
    float s = 0.f;
    if (k < 8) {
#pragma unroll
      for (int d = 0; d < 16; ++d) s = fmaf(ag[d], w3[d * 8 + k], s);
    } else {
#pragma unroll
      for (int d = 0; d < 16; ++d) s = fmaf(self[d], b3[d * 8 + (k - 8)], s);
    }
    (row ? cB : cA)[k] = s;
  }
  __syncthreads();
  if (t < 32) {
    int row = t >> 4, k = t & 15;
    const float* c = row ? cB : cA;
    float nn = 0.f;
#pragma unroll
    for (int q = 0; q < 16; ++q) nn += c[q] * c[q];
    float inv = 1.f / fmaxf(sqrtf(nn), 1e-12f);
    float v = c[k] * inv;
    (row ? dbF : daF)[k] = (v >= 0.f) ? v : 0.1f * v;
  }
  __syncthreads();
  float ue = 0.f, ve = 0.f;
#pragma unroll
  for (int i = 0; i < 16; ++i) {
    ue = fmaf(daF[i], P1[i * CDEC + t], ue);
    ve = fmaf(dbF[i], P1[i * CDEC + t], ve);
  }
  vsh[t] = ve;
  __syncthreads();
  float s = 0.f;
  for (int e2 = 0; e2 < CDEC; ++e2) s = fmaf(P2[t * CDEC + e2], vsh[e2], s);
  red[t] = s * ue;
  __syncthreads();
  for (int off = 64; off; off >>= 1) {
    if (t < off) red[t] += red[t + off];
    __syncthreads();
  }
  if (t == 0) y[b] = red[0];
}

extern "C" void kernel_launch(void* const* d_in, const int* in_sizes, int n_in,
                              void* d_out, int out_size, void* d_ws, size_t ws_size,
                              hipStream_t stream) {
  const float* x  = (const float*)d_in[0];
  const int*   adj = (const int*)d_in[1];
  const float* W  = (const float*)d_in[3];
  const float* a  = (const float*)d_in[4];
  const float* w1 = (const float*)d_in[5];
  const float* b1 = (const float*)d_in[6];
  const float* w2 = (const float*)d_in[7];
  const float* b2 = (const float*)d_in[8];
  const float* w3 = (const float*)d_in[9];
  const float* b3 = (const float*)d_in[10];
  const float* P1 = (const float*)d_in[11];
  const float* P2 = (const float*)d_in[12];
  float* y = (float*)d_out;

  char* base = (char*)d_ws;
  size_t off = 0;
  auto alloc = [&](size_t bytes) -> void* {
    void* r = base + off;
    off += (bytes + 255) & ~(size_t)255;
    return r;
  };
  float4* pk = (float4*)alloc(sizeof(float4) * CBN);
  float4* qk = (float4*)alloc(sizeof(float4) * CBN);
  unsigned long long* maskT =
      (unsigned long long*)alloc(sizeof(unsigned long long) * (size_t)CBN * NWRD);
  float* out1  = (float*)alloc(sizeof(float) * (size_t)CBN * 16);
  float* part1 = (float*)alloc(sizeof(float) * (size_t)JSP * CBN * 8);
  float* part2 = (float*)alloc(sizeof(float) * (size_t)JSP * CBN * 8);
  float* gpart = (float*)alloc(sizeof(float) * CB * 8 * 2 * 16);
  float* self2 = (float*)alloc(sizeof(float) * CB * 2 * 16);

  hipLaunchKernelGGL(prep_k, dim3(CBN / 256), dim3(256), 0, stream, x, W, a, pk, qk);
  hipLaunchKernelGGL(maskb_k, dim3(CBN / 4), dim3(256), 0, stream, adj, maskT);
  hipLaunchKernelGGL(rowsum_k, dim3(CBN / 64), dim3(256), 0, stream, maskT, pk, qk);
  hipLaunchKernelGGL(agg8_k, dim3(JSP, 4, CB), dim3(256), 0, stream, x, maskT, pk, qk, w1, part1);
  hipLaunchKernelGGL(agg16e_k, dim3(JSP, 4, CB), dim3(256), 0, stream,
                     x, part1, maskT, pk, qk, b1, w2, out1, part2);
  hipLaunchKernelGGL(epi16f_k, dim3(CBN / 256), dim3(256), 0, stream,
                     out1, part2, maskT, pk, qk, b2, gpart, self2);
  hipLaunchKernelGGL(dec_k, dim3(CB), dim3(CDEC), 0, stream,
                     gpart, self2, pk, w3, b3, P1, P2, y);
}